// Round 1
// baseline (104.782 us; speedup 1.0000x reference)
//
#include <hip/hip_runtime.h>
#include <hip/hip_bf16.h>

#define NPTS 4096
#define DIMP 17   // DIM+1

// Pass 1: accumulate F (un-clipped) and raw E-sum into out via atomics.
// Grid: (NPTS/64, NJSPLIT), block 256 = 4 waves.
// All 4 waves share the same 64 i's (lane -> i); each wave owns a 64-j chunk.
// h_j is wave-uniform -> scalar/L1-broadcast loads, no LDS in inner loop.
__global__ __launch_bounds__(256) void hydra_pair_kernel(
    const float* __restrict__ h, float* __restrict__ out) {
    const int lane = threadIdx.x & 63;
    const int wid  = threadIdx.x >> 6;
    const int i0   = blockIdx.x * 64;
    const int i    = i0 + lane;
    const int j0   = blockIdx.y * 256 + wid * 64;

    float hi[DIMP];
#pragma unroll
    for (int k = 0; k < DIMP; ++k) hi[k] = h[i * DIMP + k];

    float acc[DIMP];
#pragma unroll
    for (int k = 0; k < DIMP; ++k) acc[k] = 0.0f;
    float sacc = 0.0f;  // sum_j C_ij * inn_ij
    float eacc = 0.0f;  // sum_j V_ij

    for (int jj = 0; jj < 64; ++jj) {
        const int j = j0 + jj;             // wave-uniform
        const float* hj = h + j * DIMP;
        float hjv[DIMP];
#pragma unroll
        for (int k = 0; k < DIMP; ++k) hjv[k] = hj[k];

        // Lorentz inner product: inn = -t_i t_j + <s_i, s_j>
        float sp = 0.0f;
#pragma unroll
        for (int k = 1; k < DIMP; ++k) sp = fmaf(hi[k], hjv[k], sp);
        const float mt  = hi[0] * hjv[0];
        const float inn = sp - mt;
        const float m   = mt - sp;               // -inn = cosh(d)

        // acosh via x = m-1 (exact subtraction region), s2 = x(x+2) = m^2-1
        const float x  = fmaxf(m - 1.0f, 1e-7f); // clamp(-inn, 1+eps)
        const float s2 = x * (x + 2.0f);
        const float r  = __builtin_amdgcn_rsqf(s2);   // 1/sqrt(m^2-1) = 1/denom
        const float sq = s2 * r;                      // sqrt(m^2-1)
        const float d  = __logf(1.0f + x + sq);       // acosh(m)

        // pairwise_dist: add D_MIN where d < D_MIN (off-diag)
        const float Dp = (d < 0.08f) ? (d + 0.08f) : d;   // == D_eff off-diag

        // shared exponentials: t = e^{-Dp/2}, u = t^4 = e^{-2Dp}
        const float t = __expf(-0.5f * Dp);
        float u = t * t; u = u * u;
        // sigmoid((6-Dp)/0.5) = u / (u + e^{-12})
        const float sig = u * __builtin_amdgcn_rcpf(u + 6.144212353328210e-6f);
        const float K   = fmaf(0.5f, t, -2.0f * u) * sig; // -dVdd * sigmoid
        float C = K * d * r;                              // K * D / denom
        float V = t - u;                                  // LJ potential
        if (j == i) { C = 0.0f; V = 0.0f; }               // diagonal mask

        eacc += V;
        sacc = fmaf(C, inn, sacc);
#pragma unroll
        for (int k = 0; k < DIMP; ++k) acc[k] = fmaf(C, hjv[k], acc[k]);
    }

    // fold in the (sum_j C*inn) * h_i term
#pragma unroll
    for (int k = 0; k < DIMP; ++k) acc[k] = fmaf(sacc, hi[k], acc[k]);

    // E: wave reduction
#pragma unroll
    for (int off = 32; off > 0; off >>= 1) eacc += __shfl_xor(eacc, off);

    // cross-wave reduction in LDS, then one atomic per (i,k) per block
    __shared__ float red[3][64][DIMP];
    __shared__ float ered[4];
    if (wid > 0) {
#pragma unroll
        for (int k = 0; k < DIMP; ++k) red[wid - 1][lane][k] = acc[k];
    }
    if (lane == 0) ered[wid] = eacc;
    __syncthreads();
    if (wid == 0) {
#pragma unroll
        for (int k = 0; k < DIMP; ++k) {
            const float v = acc[k] + red[0][lane][k] + red[1][lane][k] + red[2][lane][k];
            atomicAdd(&out[(i0 + lane) * DIMP + k], v);
        }
        if (lane == 0) {
            atomicAdd(&out[NPTS * DIMP], ered[0] + ered[1] + ered[2] + ered[3]);
        }
    }
}

// Pass 2: clip ||F_i|| to 6, scale E by 0.5
__global__ __launch_bounds__(256) void hydra_finalize_kernel(float* __restrict__ out) {
    const int i = blockIdx.x * blockDim.x + threadIdx.x;
    if (i < NPTS) {
        float v[DIMP];
        float ss = 0.0f;
#pragma unroll
        for (int k = 0; k < DIMP; ++k) {
            v[k] = out[i * DIMP + k];
            ss = fmaf(v[k], v[k], ss);
        }
        const float nrm   = sqrtf(ss);
        const float scale = fminf(6.0f / fmaxf(nrm, 1e-8f), 1.0f);
#pragma unroll
        for (int k = 0; k < DIMP; ++k) out[i * DIMP + k] = v[k] * scale;
    }
    if (blockIdx.x == 0 && threadIdx.x == 0) out[NPTS * DIMP] *= 0.5f;
}

extern "C" void kernel_launch(void* const* d_in, const int* in_sizes, int n_in,
                              void* d_out, int out_size, void* d_ws, size_t ws_size,
                              hipStream_t stream) {
    const float* h = (const float*)d_in[0];
    float* out = (float*)d_out;

    // accumulators must start at zero every call (replays don't re-poison)
    hipMemsetAsync(d_out, 0, (size_t)out_size * sizeof(float), stream);

    dim3 grid(NPTS / 64, 16);
    hydra_pair_kernel<<<grid, 256, 0, stream>>>(h, out);
    hydra_finalize_kernel<<<NPTS / 256, 256, 0, stream>>>(out);
}

// Round 2
// 58.728 us; speedup vs baseline: 1.7842x; 1.7842x over previous
//
#include <hip/hip_runtime.h>

#define NPTS 4096
#define DIMP 17                     // DIM+1
#define ROWP 20                     // padded LDS/ws row (80 B, 16B-aligned)
#define JPB  128                    // j's per block (32 per wave)
#define NSLAB (NPTS / JPB)          // 32 j-slabs
#define NIB   (NPTS / 64)           // 64 i-blocks
#define EOFF  (NSLAB * NPTS * ROWP) // float offset of E partials in ws
#define NEP   (NIB * NSLAB)         // 2048 E partials

// Pass 1: grid (NIB, NSLAB), block 256 = 4 waves.
// All 4 waves share 64 i's (lane -> i); each wave owns 32 j's of the block's
// 128-j tile, which is staged into LDS once (coalesced), then read as
// wave-uniform broadcast float4s (ds_read_b128, no conflicts).
__global__ __launch_bounds__(256) void hydra_pair_kernel(
    const float* __restrict__ h, float* __restrict__ ws,
    float* __restrict__ out, const int use_ws) {
    const int lane  = threadIdx.x & 63;
    const int wid   = threadIdx.x >> 6;
    const int i0    = blockIdx.x * 64;
    const int i     = i0 + lane;
    const int jbase = blockIdx.y * JPB;

    __shared__ float lds[3 * 64 * DIMP + 8];   // 13088 B; stage uses 128*20=2560 floats

    // cooperative coalesced stage of the j-tile (row-padded to ROWP)
    for (int idx = threadIdx.x; idx < JPB * DIMP; idx += 256) {
        const int j = idx / DIMP;
        const int k = idx - j * DIMP;
        lds[j * ROWP + k] = h[jbase * DIMP + idx];
    }

    float hi[DIMP];
#pragma unroll
    for (int k = 0; k < DIMP; ++k) hi[k] = h[i * DIMP + k];

    __syncthreads();

    float acc[DIMP];
#pragma unroll
    for (int k = 0; k < DIMP; ++k) acc[k] = 0.0f;
    float sacc = 0.0f;  // sum_j C_ij * inn_ij
    float eacc = 0.0f;  // sum_j V_ij

    const int jl0 = wid * (JPB / 4);
#pragma unroll 2
    for (int jj = 0; jj < JPB / 4; ++jj) {
        const int jl = jl0 + jj;                     // wave-uniform
        const float* row = &lds[jl * ROWP];
        const float4 a0 = *(const float4*)(row);
        const float4 a1 = *(const float4*)(row + 4);
        const float4 a2 = *(const float4*)(row + 8);
        const float4 a3 = *(const float4*)(row + 12);
        const float a16 = row[16];
        const float hj[DIMP] = {a0.x, a0.y, a0.z, a0.w, a1.x, a1.y, a1.z, a1.w,
                                a2.x, a2.y, a2.z, a2.w, a3.x, a3.y, a3.z, a3.w, a16};

        // Lorentz inner product, 4-way split chains for ILP
        float sp0 = hi[1] * hj[1];
        float sp1 = hi[2] * hj[2];
        float sp2 = hi[3] * hj[3];
        float sp3 = hi[4] * hj[4];
#pragma unroll
        for (int k = 5; k < DIMP; k += 4) {
            sp0 = fmaf(hi[k    ], hj[k    ], sp0);
            sp1 = fmaf(hi[k + 1], hj[k + 1], sp1);
            sp2 = fmaf(hi[k + 2], hj[k + 2], sp2);
            sp3 = fmaf(hi[k + 3], hj[k + 3], sp3);
        }
        const float sp  = (sp0 + sp1) + (sp2 + sp3);
        const float mt  = hi[0] * hj[0];
        const float inn = sp - mt;
        const float m   = mt - sp;                   // -inn = cosh(d)

        // acosh via x = m-1; s2 = x(x+2) = m^2-1 (no cancellation)
        const float x  = fmaxf(m - 1.0f, 1e-7f);
        const float s2 = x * (x + 2.0f);
        const float r  = __builtin_amdgcn_rsqf(s2);  // 1/denom
        const float sq = s2 * r;
        const float d  = __logf(1.0f + x + sq);      // acosh(m)

        const float Dp = (d < 0.08f) ? (d + 0.08f) : d;

        const float t = __expf(-0.5f * Dp);          // e^{-Dp/2}
        float u = t * t; u = u * u;                  // e^{-2Dp}
        const float sig = u * __builtin_amdgcn_rcpf(u + 6.144212353328210e-6f);
        const float K   = fmaf(0.5f, t, -2.0f * u) * sig;
        float C = K * d * r;
        float V = t - u;
        if (jbase + jl == i) { C = 0.0f; V = 0.0f; } // diagonal

        eacc += V;
        sacc = fmaf(C, inn, sacc);
#pragma unroll
        for (int k = 0; k < DIMP; ++k) acc[k] = fmaf(C, hj[k], acc[k]);
    }

#pragma unroll
    for (int k = 0; k < DIMP; ++k) acc[k] = fmaf(sacc, hi[k], acc[k]);
#pragma unroll
    for (int off = 32; off > 0; off >>= 1) eacc += __shfl_xor(eacc, off);

    __syncthreads();   // tile reads done; reuse LDS for reduction
    if (wid > 0) {
#pragma unroll
        for (int k = 0; k < DIMP; ++k)
            lds[((wid - 1) * 64 + lane) * DIMP + k] = acc[k];
    }
    if (lane == 0 && wid > 0) lds[3 * 64 * DIMP + wid] = eacc;
    __syncthreads();

    if (wid == 0) {
        const float esum = eacc + lds[3 * 64 * DIMP + 1] +
                           lds[3 * 64 * DIMP + 2] + lds[3 * 64 * DIMP + 3];
        if (use_ws) {
            float* dst = ws + ((size_t)blockIdx.y * NPTS + i) * ROWP;
#pragma unroll
            for (int k = 0; k < DIMP; ++k)
                dst[k] = acc[k] + lds[(0 * 64 + lane) * DIMP + k]
                                + lds[(1 * 64 + lane) * DIMP + k]
                                + lds[(2 * 64 + lane) * DIMP + k];
            if (lane == 0) ws[EOFF + blockIdx.y * NIB + blockIdx.x] = esum;
        } else {
#pragma unroll
            for (int k = 0; k < DIMP; ++k) {
                const float v = acc[k] + lds[(0 * 64 + lane) * DIMP + k]
                                       + lds[(1 * 64 + lane) * DIMP + k]
                                       + lds[(2 * 64 + lane) * DIMP + k];
                atomicAdd(&out[i * DIMP + k], v);
            }
            if (lane == 0) atomicAdd(&out[NPTS * DIMP], esum);
        }
    }
}

// Pass 2: reduce slab partials, clip ||F_i|| to 6, write E*0.5
__global__ __launch_bounds__(256) void hydra_finalize_kernel(
    const float* __restrict__ ws, float* __restrict__ out, const int use_ws) {
    const int i = blockIdx.x * 256 + threadIdx.x;
    float v[DIMP];
    if (use_ws) {
#pragma unroll
        for (int k = 0; k < DIMP; ++k) v[k] = 0.0f;
        for (int s = 0; s < NSLAB; ++s) {
            const float* row = ws + ((size_t)s * NPTS + i) * ROWP;
            const float4 b0 = *(const float4*)(row);
            const float4 b1 = *(const float4*)(row + 4);
            const float4 b2 = *(const float4*)(row + 8);
            const float4 b3 = *(const float4*)(row + 12);
            const float b16 = row[16];
            v[0] += b0.x; v[1] += b0.y; v[2]  += b0.z; v[3]  += b0.w;
            v[4] += b1.x; v[5] += b1.y; v[6]  += b1.z; v[7]  += b1.w;
            v[8] += b2.x; v[9] += b2.y; v[10] += b2.z; v[11] += b2.w;
            v[12] += b3.x; v[13] += b3.y; v[14] += b3.z; v[15] += b3.w;
            v[16] += b16;
        }
    } else {
#pragma unroll
        for (int k = 0; k < DIMP; ++k) v[k] = out[i * DIMP + k];
    }

    float ss = 0.0f;
#pragma unroll
    for (int k = 0; k < DIMP; ++k) ss = fmaf(v[k], v[k], ss);
    const float nrm   = sqrtf(ss);
    const float scale = fminf(6.0f / fmaxf(nrm, 1e-8f), 1.0f);
#pragma unroll
    for (int k = 0; k < DIMP; ++k) out[i * DIMP + k] = v[k] * scale;

    if (blockIdx.x == 0) {
        if (use_ws) {
            float e = 0.0f;
            for (int t = threadIdx.x; t < NEP; t += 256) e += ws[EOFF + t];
#pragma unroll
            for (int off = 32; off > 0; off >>= 1) e += __shfl_xor(e, off);
            __shared__ float es[4];
            if ((threadIdx.x & 63) == 0) es[threadIdx.x >> 6] = e;
            __syncthreads();
            if (threadIdx.x == 0)
                out[NPTS * DIMP] = 0.5f * (es[0] + es[1] + es[2] + es[3]);
        } else {
            if (threadIdx.x == 0) out[NPTS * DIMP] *= 0.5f;
        }
    }
}

extern "C" void kernel_launch(void* const* d_in, const int* in_sizes, int n_in,
                              void* d_out, int out_size, void* d_ws, size_t ws_size,
                              hipStream_t stream) {
    const float* h = (const float*)d_in[0];
    float* out = (float*)d_out;
    float* ws  = (float*)d_ws;

    const size_t need = (size_t)(EOFF + NEP) * sizeof(float);
    const int use_ws = (ws_size >= need) ? 1 : 0;
    if (!use_ws) {
        // atomic fallback needs zeroed accumulators every call
        hipMemsetAsync(d_out, 0, (size_t)out_size * sizeof(float), stream);
    }

    dim3 grid(NIB, NSLAB);
    hydra_pair_kernel<<<grid, 256, 0, stream>>>(h, ws, out, use_ws);
    hydra_finalize_kernel<<<NPTS / 256, 256, 0, stream>>>(ws, out, use_ws);
}

// Round 3
// 39.032 us; speedup vs baseline: 2.6845x; 1.5046x over previous
//
#include <hip/hip_runtime.h>

#define NPTS 4096
#define DIMP 17                     // DIM+1
#define ROWP 20                     // padded row (80 B, 16B-aligned)
#define JPB  256                    // j's per block (64 per wave)
#define NSLAB (NPTS / JPB)          // 16 j-slabs
#define NIB   (NPTS / 64)           // 64 i-blocks
#define EOFF  (NSLAB * NPTS * ROWP) // float offset of E partials in ws
#define NEP   (NIB * NSLAB)         // 1024 E partials
#define EDIAG 445.0126f             // 4096 * (e^{-0.04} - e^{-0.16})

typedef float v2f __attribute__((ext_vector_type(2)));
typedef float v4f __attribute__((ext_vector_type(4)));

// Pass 1: grid (NIB, NSLAB), block 256 = 4 waves, 4 blocks/CU.
// All waves share 64 i's (lane -> i); each wave owns 64 j's of the block's
// 256-j LDS tile. Inner loop: packed-fp32 dot/acc, no diagonal branch.
__global__ __launch_bounds__(256, 4) void hydra_pair_kernel(
    const float* __restrict__ h, float* __restrict__ ws,
    float* __restrict__ out, const int use_ws) {
    const int tid   = threadIdx.x;
    const int lane  = tid & 63;
    const int wid   = tid >> 6;
    const int i     = blockIdx.x * 64 + lane;
    const int jbase = blockIdx.y * JPB;

    __shared__ __align__(16) float lds[JPB * ROWP + 8];

    // coalesced stage of the j-tile (rows padded to ROWP)
#pragma unroll
    for (int kk = 0; kk < DIMP; ++kk) {
        const int idx = tid + kk * 256;
        const int j = idx / DIMP;
        const int k = idx - j * DIMP;
        lds[j * ROWP + k] = h[jbase * DIMP + idx];
    }

    // h_i with time component pre-negated -> Lorentz dot is a pure fma chain
    float hraw[DIMP];
#pragma unroll
    for (int k = 0; k < DIMP; ++k) hraw[k] = h[i * DIMP + k];
    v2f hi2[8];
#pragma unroll
    for (int p = 0; p < 8; ++p) { hi2[p].x = hraw[2 * p]; hi2[p].y = hraw[2 * p + 1]; }
    hi2[0].x = -hi2[0].x;
    const float hi16 = hraw[16];

    __syncthreads();

    v2f acc2[8];
#pragma unroll
    for (int p = 0; p < 8; ++p) acc2[p] = (v2f)(0.0f);
    float acc16 = 0.0f;
    float sacc  = 0.0f;   // sum_j C * inn
    float eacc  = 0.0f;   // sum_j V

    const float* rowp = lds + wid * 64 * ROWP;
#pragma unroll 2
    for (int jj = 0; jj < JPB / 4; ++jj, rowp += ROWP) {
        const v4f a0 = ((const v4f*)rowp)[0];
        const v4f a1 = ((const v4f*)rowp)[1];
        const v4f a2 = ((const v4f*)rowp)[2];
        const v4f a3 = ((const v4f*)rowp)[3];
        const float a16 = rowp[16];
        v2f b[8];
        b[0].x = a0.x; b[0].y = a0.y;  b[1].x = a0.z; b[1].y = a0.w;
        b[2].x = a1.x; b[2].y = a1.y;  b[3].x = a1.z; b[3].y = a1.w;
        b[4].x = a2.x; b[4].y = a2.y;  b[5].x = a2.z; b[5].y = a2.w;
        b[6].x = a3.x; b[6].y = a3.y;  b[7].x = a3.z; b[7].y = a3.w;

        // g = <h_i, h_j>_Lorentz  (packed fma, 2 chains)
        v2f c0 = hi2[0] * b[0];
        v2f c1 = hi2[1] * b[1];
        c0 = __builtin_elementwise_fma(hi2[2], b[2], c0);
        c1 = __builtin_elementwise_fma(hi2[3], b[3], c1);
        c0 = __builtin_elementwise_fma(hi2[4], b[4], c0);
        c1 = __builtin_elementwise_fma(hi2[5], b[5], c1);
        c0 = __builtin_elementwise_fma(hi2[6], b[6], c0);
        c1 = __builtin_elementwise_fma(hi2[7], b[7], c1);
        const v2f cs = c0 + c1;
        const float g = fmaf(hi16, a16, cs.x + cs.y);   // = inn, cosh(d) = -g

        // acosh without cancellation: x = cosh-1, s2 = x(x+2) = sinh^2
        const float x  = fmaxf(-1.0f - g, 1e-7f);
        const float s2 = x * (x + 2.0f);
        const float r  = __builtin_amdgcn_rsqf(s2);     // 1/sinh
        const float sq = s2 * r;                        // sinh
        const float w  = (x - sq) + 1.0f;               // e^{-d}
        const float d  = -__logf(w);

        // D_pair shift (d<0.08 -> d+0.08) folded into t via constant factor
        const float fac = (d < 0.08f) ? 0.96078944f : 1.0f;   // e^{-0.04}
        const float t = __builtin_amdgcn_sqrtf(w) * fac;      // e^{-Dp/2}
        float u = t * t; u = u * u;                           // e^{-2Dp}
        const float sig = u * __builtin_amdgcn_rcpf(u + 6.1442123533e-6f);
        const float K   = fmaf(0.5f, t, -2.0f * u) * sig;     // -dVdd * sigmoid
        const float C   = K * d * r;

        eacc += (t - u);
        sacc = fmaf(C, g, sacc);
        const v2f C2 = {C, C};
#pragma unroll
        for (int p = 0; p < 8; ++p)
            acc2[p] = __builtin_elementwise_fma(C2, b[p], acc2[p]);
        acc16 = fmaf(C, a16, acc16);
    }

    // fold (sum C*inn) * h_i  (h_i time component is negated in hi2[0].x)
    const v2f s2v = {sacc, sacc};
#pragma unroll
    for (int p = 1; p < 8; ++p)
        acc2[p] = __builtin_elementwise_fma(s2v, hi2[p], acc2[p]);
    acc2[0].x = fmaf(-sacc, hi2[0].x, acc2[0].x);
    acc2[0].y = fmaf( sacc, hi2[0].y, acc2[0].y);
    acc16 = fmaf(sacc, hi16, acc16);

#pragma unroll
    for (int off = 32; off > 0; off >>= 1) eacc += __shfl_xor(eacc, off);

    __syncthreads();   // tile reads done; reuse LDS for cross-wave reduction
    if (wid > 0) {
        float* dst = lds + ((wid - 1) * 64 + lane) * ROWP;
#pragma unroll
        for (int p = 0; p < 8; ++p) ((v2f*)dst)[p] = acc2[p];
        dst[16] = acc16;
    }
    if (lane == 0 && wid > 0) lds[JPB * ROWP + wid] = eacc;
    __syncthreads();

    if (wid == 0) {
        const float esum = eacc + lds[JPB * ROWP + 1] + lds[JPB * ROWP + 2] +
                           lds[JPB * ROWP + 3];
#pragma unroll
        for (int q = 0; q < 3; ++q) {
            const float* src = lds + (q * 64 + lane) * ROWP;
#pragma unroll
            for (int p = 0; p < 8; ++p) acc2[p] += ((const v2f*)src)[p];
            acc16 += src[16];
        }
        if (use_ws) {
            float* dst = ws + ((size_t)blockIdx.y * NPTS + i) * ROWP;
#pragma unroll
            for (int p = 0; p < 8; ++p) ((v2f*)dst)[p] = acc2[p];
            dst[16] = acc16;
            if (lane == 0) ws[EOFF + blockIdx.y * NIB + blockIdx.x] = esum;
        } else {
#pragma unroll
            for (int p = 0; p < 8; ++p) {
                atomicAdd(&out[i * DIMP + 2 * p],     acc2[p].x);
                atomicAdd(&out[i * DIMP + 2 * p + 1], acc2[p].y);
            }
            atomicAdd(&out[i * DIMP + 16], acc16);
            if (lane == 0) atomicAdd(&out[NPTS * DIMP], esum);
        }
    }
}

// Pass 2: grid 64 blocks x 256. lane -> i (64 per block), wid -> slab quarter.
__global__ __launch_bounds__(256) void hydra_finalize_kernel(
    const float* __restrict__ ws, float* __restrict__ out, const int use_ws) {
    const int tid  = threadIdx.x;
    const int lane = tid & 63;
    const int q    = tid >> 6;
    const int i    = blockIdx.x * 64 + lane;

    __shared__ __align__(16) float red[3 * 64 * ROWP + 8];

    float v[DIMP];
#pragma unroll
    for (int k = 0; k < DIMP; ++k) v[k] = 0.0f;

    if (use_ws) {
#pragma unroll
        for (int ss = 0; ss < NSLAB / 4; ++ss) {
            const int s = q * (NSLAB / 4) + ss;
            const float* row = ws + ((size_t)s * NPTS + i) * ROWP;
            const v4f b0 = ((const v4f*)row)[0];
            const v4f b1 = ((const v4f*)row)[1];
            const v4f b2 = ((const v4f*)row)[2];
            const v4f b3 = ((const v4f*)row)[3];
            v[0]  += b0.x; v[1]  += b0.y; v[2]  += b0.z; v[3]  += b0.w;
            v[4]  += b1.x; v[5]  += b1.y; v[6]  += b1.z; v[7]  += b1.w;
            v[8]  += b2.x; v[9]  += b2.y; v[10] += b2.z; v[11] += b2.w;
            v[12] += b3.x; v[13] += b3.y; v[14] += b3.z; v[15] += b3.w;
            v[16] += row[16];
        }
        if (q > 0) {
            float* dst = red + ((q - 1) * 64 + lane) * ROWP;
#pragma unroll
            for (int k = 0; k < DIMP; ++k) dst[k] = v[k];
        }
        __syncthreads();
        if (q == 0) {
#pragma unroll
            for (int qq = 0; qq < 3; ++qq) {
                const float* src = red + (qq * 64 + lane) * ROWP;
#pragma unroll
                for (int k = 0; k < DIMP; ++k) v[k] += src[k];
            }
        }
    } else if (q == 0) {
#pragma unroll
        for (int k = 0; k < DIMP; ++k) v[k] = out[i * DIMP + k];
    }

    if (q == 0) {
        float ss = 0.0f;
#pragma unroll
        for (int k = 0; k < DIMP; ++k) ss = fmaf(v[k], v[k], ss);
        const float nrm   = sqrtf(ss);
        const float scale = fminf(6.0f / fmaxf(nrm, 1e-8f), 1.0f);
#pragma unroll
        for (int k = 0; k < DIMP; ++k) out[i * DIMP + k] = v[k] * scale;
    }

    if (blockIdx.x == 0) {
        if (use_ws) {
            float e = 0.0f;
#pragma unroll
            for (int t = 0; t < NEP / 256; ++t) e += ws[EOFF + tid + t * 256];
#pragma unroll
            for (int off = 32; off > 0; off >>= 1) e += __shfl_xor(e, off);
            __shared__ float es[4];
            if (lane == 0) es[q] = e;
            __syncthreads();
            if (tid == 0)
                out[NPTS * DIMP] = 0.5f * ((es[0] + es[1] + es[2] + es[3]) - EDIAG);
        } else {
            if (tid == 0) out[NPTS * DIMP] = 0.5f * (out[NPTS * DIMP] - EDIAG);
        }
    }
}

extern "C" void kernel_launch(void* const* d_in, const int* in_sizes, int n_in,
                              void* d_out, int out_size, void* d_ws, size_t ws_size,
                              hipStream_t stream) {
    const float* h = (const float*)d_in[0];
    float* out = (float*)d_out;
    float* ws  = (float*)d_ws;

    const size_t need = (size_t)(EOFF + NEP) * sizeof(float);
    const int use_ws = (ws_size >= need) ? 1 : 0;
    if (!use_ws) {
        hipMemsetAsync(d_out, 0, (size_t)out_size * sizeof(float), stream);
    }

    dim3 grid(NIB, NSLAB);
    hydra_pair_kernel<<<grid, 256, 0, stream>>>(h, ws, out, use_ws);
    hydra_finalize_kernel<<<64, 256, 0, stream>>>(ws, out, use_ws);
}

// Round 4
// 39.004 us; speedup vs baseline: 2.6864x; 1.0007x over previous
//
#include <hip/hip_runtime.h>

#define NPTS 4096
#define DIMP 17                     // DIM+1
#define ROWP 20                     // padded row (80 B, 16B-aligned)
#define JPB  256                    // j's per block (32 per wave, 8 waves)
#define NSLAB (NPTS / JPB)          // 16 j-slabs
#define NIB   (NPTS / 64)           // 64 i-blocks
#define EOFF  (NSLAB * NPTS * ROWP) // float offset of E partials in ws
#define NEP   (NIB * NSLAB)         // 1024 E partials
#define EDIAG 445.0126f             // 4096 * (e^{-0.04} - e^{-0.16})
#define REDROWS (7 * 64)            // cross-wave reduction rows in LDS

typedef float v2f __attribute__((ext_vector_type(2)));
typedef float v4f __attribute__((ext_vector_type(4)));

// Pass 1: grid (NIB, NSLAB), block 512 = 8 waves.
// All waves share 64 i's (lane -> i); each wave owns 32 j's of the block's
// 256-j LDS tile. Rotated prefetch: next row's LDS reads issue before this
// row's compute chain, so ds_read latency hides under ALU.
__global__ __launch_bounds__(512) void hydra_pair_kernel(
    const float* __restrict__ h, float* __restrict__ ws,
    float* __restrict__ out, const int use_ws) {
    const int tid   = threadIdx.x;
    const int lane  = tid & 63;
    const int wid   = tid >> 6;                 // 0..7
    const int i     = blockIdx.x * 64 + lane;
    const int jbase = blockIdx.y * JPB;

    // reduction area (7*64 rows) overlaps/extends the 256-row tile area;
    // +16 floats of E scratch at the tail. 35968 B total.
    __shared__ __align__(16) float lds[REDROWS * ROWP + 16];

    // coalesced stage of the 256-j tile (rows padded to ROWP)
    for (int idx = tid; idx < JPB * DIMP; idx += 512) {
        const int j = idx / DIMP;
        const int k = idx - j * DIMP;
        lds[j * ROWP + k] = h[jbase * DIMP + idx];
    }

    // h_i with time component pre-negated -> Lorentz dot is a pure fma chain
    float hraw[DIMP];
#pragma unroll
    for (int k = 0; k < DIMP; ++k) hraw[k] = h[i * DIMP + k];
    v2f hi2[8];
#pragma unroll
    for (int p = 0; p < 8; ++p) { hi2[p].x = hraw[2 * p]; hi2[p].y = hraw[2 * p + 1]; }
    hi2[0].x = -hi2[0].x;
    const float hi16 = hraw[16];

    __syncthreads();

    v2f acc2[8];
#pragma unroll
    for (int p = 0; p < 8; ++p) acc2[p] = (v2f)(0.0f);
    float acc16 = 0.0f;
    float sacc  = 0.0f;   // sum_j C * inn
    float eacc  = 0.0f;   // sum_j V

    const float* rowp = lds + (wid * 32) * ROWP;
    // prefetch row 0
    v4f n0 = ((const v4f*)rowp)[0];
    v4f n1 = ((const v4f*)rowp)[1];
    v4f n2 = ((const v4f*)rowp)[2];
    v4f n3 = ((const v4f*)rowp)[3];
    float n16 = rowp[16];

#pragma unroll 2
    for (int jj = 0; jj < 32; ++jj) {
        const v4f a0 = n0, a1 = n1, a2 = n2, a3 = n3;
        const float a16 = n16;
        rowp += ROWP;
        // prefetch next row (last iteration reads the pad row — never used)
        n0 = ((const v4f*)rowp)[0];
        n1 = ((const v4f*)rowp)[1];
        n2 = ((const v4f*)rowp)[2];
        n3 = ((const v4f*)rowp)[3];
        n16 = rowp[16];

        // g = <h_i, h_j>_Lorentz  (packed fma, 2 chains)
        v2f c0 = hi2[0] * a0.lo;
        v2f c1 = hi2[1] * a0.hi;
        c0 = __builtin_elementwise_fma(hi2[2], a1.lo, c0);
        c1 = __builtin_elementwise_fma(hi2[3], a1.hi, c1);
        c0 = __builtin_elementwise_fma(hi2[4], a2.lo, c0);
        c1 = __builtin_elementwise_fma(hi2[5], a2.hi, c1);
        c0 = __builtin_elementwise_fma(hi2[6], a3.lo, c0);
        c1 = __builtin_elementwise_fma(hi2[7], a3.hi, c1);
        const v2f cs = c0 + c1;
        const float g = fmaf(hi16, a16, cs.x + cs.y);   // = inn, cosh(d) = -g

        // acosh without cancellation: x = cosh-1, s2 = x(x+2) = sinh^2
        const float x  = fmaxf(-1.0f - g, 1e-7f);
        const float s2 = x * (x + 2.0f);
        const float r  = __builtin_amdgcn_rsqf(s2);     // 1/sinh
        const float sq = s2 * r;                        // sinh
        const float w  = (x - sq) + 1.0f;               // e^{-d}
        const float d  = -__logf(w);

        // D_pair shift (d<0.08 -> d+0.08) folded into t via constant factor
        const float fac = (d < 0.08f) ? 0.96078944f : 1.0f;   // e^{-0.04}
        const float t = __builtin_amdgcn_sqrtf(w) * fac;      // e^{-Dp/2}
        float u = t * t; u = u * u;                           // e^{-2Dp}
        const float sig = u * __builtin_amdgcn_rcpf(u + 6.1442123533e-6f);
        const float K   = fmaf(0.5f, t, -2.0f * u) * sig;     // -dVdd * sigmoid
        const float C   = K * d * r;

        eacc += (t - u);
        sacc = fmaf(C, g, sacc);
        const v2f C2 = {C, C};
        acc2[0] = __builtin_elementwise_fma(C2, a0.lo, acc2[0]);
        acc2[1] = __builtin_elementwise_fma(C2, a0.hi, acc2[1]);
        acc2[2] = __builtin_elementwise_fma(C2, a1.lo, acc2[2]);
        acc2[3] = __builtin_elementwise_fma(C2, a1.hi, acc2[3]);
        acc2[4] = __builtin_elementwise_fma(C2, a2.lo, acc2[4]);
        acc2[5] = __builtin_elementwise_fma(C2, a2.hi, acc2[5]);
        acc2[6] = __builtin_elementwise_fma(C2, a3.lo, acc2[6]);
        acc2[7] = __builtin_elementwise_fma(C2, a3.hi, acc2[7]);
        acc16 = fmaf(C, a16, acc16);
    }

    // fold (sum C*inn) * h_i  (h_i time component is negated in hi2[0].x)
    const v2f s2v = {sacc, sacc};
#pragma unroll
    for (int p = 1; p < 8; ++p)
        acc2[p] = __builtin_elementwise_fma(s2v, hi2[p], acc2[p]);
    acc2[0].x = fmaf(-sacc, hi2[0].x, acc2[0].x);
    acc2[0].y = fmaf( sacc, hi2[0].y, acc2[0].y);
    acc16 = fmaf(sacc, hi16, acc16);

#pragma unroll
    for (int off = 32; off > 0; off >>= 1) eacc += __shfl_xor(eacc, off);

    __syncthreads();   // all waves done reading tile; reuse LDS for reduction
    if (wid > 0) {
        float* dst = lds + ((wid - 1) * 64 + lane) * ROWP;
#pragma unroll
        for (int p = 0; p < 8; ++p) ((v2f*)dst)[p] = acc2[p];
        dst[16] = acc16;
    }
    if (lane == 0) lds[REDROWS * ROWP + wid] = eacc;
    __syncthreads();

    if (wid == 0) {
        float esum = 0.0f;
#pragma unroll
        for (int q = 0; q < 8; ++q) esum += lds[REDROWS * ROWP + q];
#pragma unroll
        for (int q = 0; q < 7; ++q) {
            const float* src = lds + (q * 64 + lane) * ROWP;
#pragma unroll
            for (int p = 0; p < 8; ++p) acc2[p] += ((const v2f*)src)[p];
            acc16 += src[16];
        }
        if (use_ws) {
            float* dst = ws + ((size_t)blockIdx.y * NPTS + i) * ROWP;
#pragma unroll
            for (int p = 0; p < 8; ++p) ((v2f*)dst)[p] = acc2[p];
            dst[16] = acc16;
            if (lane == 0) ws[EOFF + blockIdx.y * NIB + blockIdx.x] = esum;
        } else {
#pragma unroll
            for (int p = 0; p < 8; ++p) {
                atomicAdd(&out[i * DIMP + 2 * p],     acc2[p].x);
                atomicAdd(&out[i * DIMP + 2 * p + 1], acc2[p].y);
            }
            atomicAdd(&out[i * DIMP + 16], acc16);
            if (lane == 0) atomicAdd(&out[NPTS * DIMP], esum);
        }
    }
}

// Pass 2: grid 64 blocks x 256. lane -> i (64 per block), wid -> slab quarter.
__global__ __launch_bounds__(256) void hydra_finalize_kernel(
    const float* __restrict__ ws, float* __restrict__ out, const int use_ws) {
    const int tid  = threadIdx.x;
    const int lane = tid & 63;
    const int q    = tid >> 6;
    const int i    = blockIdx.x * 64 + lane;

    __shared__ __align__(16) float red[3 * 64 * ROWP + 8];

    float v[DIMP];
#pragma unroll
    for (int k = 0; k < DIMP; ++k) v[k] = 0.0f;

    if (use_ws) {
#pragma unroll
        for (int ss = 0; ss < NSLAB / 4; ++ss) {
            const int s = q * (NSLAB / 4) + ss;
            const float* row = ws + ((size_t)s * NPTS + i) * ROWP;
            const v4f b0 = ((const v4f*)row)[0];
            const v4f b1 = ((const v4f*)row)[1];
            const v4f b2 = ((const v4f*)row)[2];
            const v4f b3 = ((const v4f*)row)[3];
            v[0]  += b0.x; v[1]  += b0.y; v[2]  += b0.z; v[3]  += b0.w;
            v[4]  += b1.x; v[5]  += b1.y; v[6]  += b1.z; v[7]  += b1.w;
            v[8]  += b2.x; v[9]  += b2.y; v[10] += b2.z; v[11] += b2.w;
            v[12] += b3.x; v[13] += b3.y; v[14] += b3.z; v[15] += b3.w;
            v[16] += row[16];
        }
        if (q > 0) {
            float* dst = red + ((q - 1) * 64 + lane) * ROWP;
#pragma unroll
            for (int k = 0; k < DIMP; ++k) dst[k] = v[k];
        }
        __syncthreads();
        if (q == 0) {
#pragma unroll
            for (int qq = 0; qq < 3; ++qq) {
                const float* src = red + (qq * 64 + lane) * ROWP;
#pragma unroll
                for (int k = 0; k < DIMP; ++k) v[k] += src[k];
            }
        }
    } else if (q == 0) {
#pragma unroll
        for (int k = 0; k < DIMP; ++k) v[k] = out[i * DIMP + k];
    }

    if (q == 0) {
        float ss = 0.0f;
#pragma unroll
        for (int k = 0; k < DIMP; ++k) ss = fmaf(v[k], v[k], ss);
        const float nrm   = sqrtf(ss);
        const float scale = fminf(6.0f / fmaxf(nrm, 1e-8f), 1.0f);
#pragma unroll
        for (int k = 0; k < DIMP; ++k) out[i * DIMP + k] = v[k] * scale;
    }

    if (blockIdx.x == 0) {
        if (use_ws) {
            float e = 0.0f;
#pragma unroll
            for (int t = 0; t < NEP / 256; ++t) e += ws[EOFF + tid + t * 256];
#pragma unroll
            for (int off = 32; off > 0; off >>= 1) e += __shfl_xor(e, off);
            __shared__ float es[4];
            if (lane == 0) es[q] = e;
            __syncthreads();
            if (tid == 0)
                out[NPTS * DIMP] = 0.5f * ((es[0] + es[1] + es[2] + es[3]) - EDIAG);
        } else {
            if (tid == 0) out[NPTS * DIMP] = 0.5f * (out[NPTS * DIMP] - EDIAG);
        }
    }
}

extern "C" void kernel_launch(void* const* d_in, const int* in_sizes, int n_in,
                              void* d_out, int out_size, void* d_ws, size_t ws_size,
                              hipStream_t stream) {
    const float* h = (const float*)d_in[0];
    float* out = (float*)d_out;
    float* ws  = (float*)d_ws;

    const size_t need = (size_t)(EOFF + NEP) * sizeof(float);
    const int use_ws = (ws_size >= need) ? 1 : 0;
    if (!use_ws) {
        hipMemsetAsync(d_out, 0, (size_t)out_size * sizeof(float), stream);
    }

    dim3 grid(NIB, NSLAB);
    hydra_pair_kernel<<<grid, 512, 0, stream>>>(h, ws, out, use_ws);
    hydra_finalize_kernel<<<64, 256, 0, stream>>>(ws, out, use_ws);
}